// Round 3
// baseline (256.455 us; speedup 1.0000x reference)
//
#include <hip/hip_runtime.h>

// SNN temporal scan, T=16 steps, K=8 nested thresholds. Bit-exact vs numpy f32
// (absmax 0.0 verified in R1/R2): mem update keeps reference's left-to-right
// add order; /t is a real IEEE div only where unavoidable (non-pow2 t on the
// ein path); spike/t uses one q_t = th/t per thread scaled by exact 2^-k.
//
// R3 change: depth-8 software-pipelined prefetch ring. R2 was latency-bound
// (one-ahead prefetch; VALUBusy 37%, hbm 31%, occupancy 67% -- nothing
// saturated). 8 in-flight loads/thread issue each load ~1300 cycles before
// use, covering worst-case HBM latency (~900 cyc).

#define T_STEPS 16
#define K_THRESH 8
#define PF 8  // prefetch ring depth

typedef float v2f __attribute__((ext_vector_type(2)));

__global__ __launch_bounds__(256, 8) void snn_scan_kernel(
    const float* __restrict__ x,
    const float* __restrict__ thresh_p,
    float* __restrict__ out,
    int N2)  // float2 groups per timestep slice
{
    const int i = blockIdx.x * blockDim.x + threadIdx.x;
    if (i >= N2) return;

    const float th = *thresh_p;
    const float thq0 = 0.75f * th;
    // thq[k] = 2^-k * rn(0.75*th) == reference's rn(0.75 * (th/2^k)) exactly
    float thq[K_THRESH];
#pragma unroll
    for (int k = 0; k < K_THRESH; ++k) thq[k] = __builtin_ldexpf(thq0, -k);

    const v2f* __restrict__ xv = (const v2f*)x;
    v2f* __restrict__ ov = (v2f*)out;

    // bias + prefetch ring fill: 9 loads issued back-to-back
    const v2f b2 = xv[i];
    v2f buf[PF];
#pragma unroll
    for (int p = 0; p < PF; ++p) buf[p] = xv[(1 + p) * N2 + i];

    {
        v2f z; z.x = 0.f; z.y = 0.f;
        __builtin_nontemporal_store(z, ov + i);  // output slice 0 = zeros
    }

    float mem0 = 0.f, mem1 = 0.f;
    const float bias0 = b2.x, bias1 = b2.y;
    float ein0 = bias0, ein1 = bias1;   // exp_in init = bias
    float eout0 = 0.f, eout1 = 0.f;

#pragma unroll
    for (int t = 1; t <= T_STEPS; ++t) {
        const int slot = (t - 1) % PF;           // static after unroll
        const float xi0 = buf[slot].x, xi1 = buf[slot].y;
        if (t + PF <= T_STEPS) buf[slot] = xv[(t + PF) * N2 + i];

        const bool tp2 = (t & (t - 1)) == 0;      // compile-time per iter
        const float rt = 1.0f / (float)t;         // folded constant; used iff tp2
        const float q_t = tp2 ? (th * rt)         // exact (pow2 scale)
                              : (th / (float)t);  // IEEE div, once per thread

        auto stepj = [&](float& mem, float& ein, float& eout,
                         float xi, float bias) -> float {
            // mem = mem + xi - bias + exp_in - exp_out (left-to-right)
            const float m = (((mem + xi) - bias) + ein) - eout;
            const float a = __builtin_fabsf(m);
            // first-fired threshold: smallest k with a >= thq[k]
            float sc = 0.f;
#pragma unroll
            for (int k = K_THRESH - 1; k >= 0; --k) {
                const float sck = (float)(1.0 / (double)(1 << k));  // exact 2^-k
                sc = (a >= thq[k]) ? sck : sc;
            }
            const bool pos = (m >= 0.f);
            const float mag = sc * th;            // exact: lev[k] = th*2^-k
            const float s   = pos ? mag : -mag;
            const float sq  = sc * q_t;           // exact: rn(|s|/t)
            mem = m - s;
            const float d = xi - bias;
            if (tp2) ein = ein + d * rt;          // exact == d/t for pow2 t
            else     ein = ein + d / (float)t;    // IEEE div (non-pow2 t)
            eout = eout + (pos ? sq : -sq);
            return s;
        };

        v2f sp;
        sp.x = stepj(mem0, ein0, eout0, xi0, bias0);
        sp.y = stepj(mem1, ein1, eout1, xi1, bias1);
        __builtin_nontemporal_store(sp, ov + t * N2 + i);
    }
}

extern "C" void kernel_launch(void* const* d_in, const int* in_sizes, int n_in,
                              void* d_out, int out_size, void* d_ws, size_t ws_size,
                              hipStream_t stream) {
    const float* x      = (const float*)d_in[0];
    const float* thresh = (const float*)d_in[1];
    float* out = (float*)d_out;

    const int N  = in_sizes[0] / (T_STEPS + 1);  // elements per timestep slice
    const int N2 = N / 2;                        // float2 groups

    const int block = 256;
    const int grid  = (N2 + block - 1) / block;
    snn_scan_kernel<<<grid, block, 0, stream>>>(x, thresh, out, N2);
}